// Round 2
// baseline (330.255 us; speedup 1.0000x reference)
//
#include <hip/hip_runtime.h>
#include <math.h>

#define NUM_AGENTS 256
#define HIDDEN 1024
#define RANK 32
#define MAX_TOK 8192
#define ALPHA_MAX 5.0f
#define LN_EPS 1e-5f

// One block per agent. Block scans agent_ids, builds its token list in LDS,
// then per token: inter = h . U[a]; pert = inter . V[a];
// out = LayerNorm(h + alpha*pert) * gamma + beta.  All f32.
__global__ __launch_bounds__(256) void div_inject_kernel(
    const float* __restrict__ hglob,
    const float* __restrict__ log_alpha,
    const float* __restrict__ gamma,
    const float* __restrict__ beta,
    const float* __restrict__ U,
    const float* __restrict__ V,
    const int* __restrict__ ids,
    float* __restrict__ out,
    int ntok)
{
    __shared__ int toklist[MAX_TOK];
    __shared__ int tokcount;
    __shared__ __align__(16) float hrow[HIDDEN];
    __shared__ float red[16][32];   // [h-slot][r]
    __shared__ float inter[RANK];
    __shared__ float wred[8];       // per-wave sum / sumsq
    __shared__ float stats[2];      // mean, rstd

    const int t = threadIdx.x;       // 0..255
    const int agent = blockIdx.x;    // 0..255

    if (t == 0) tokcount = 0;
    __syncthreads();

    // ---- scan agent_ids, collect this agent's tokens ----
    for (int i = t; i < ntok; i += 256) {
        int a = ids[i] % NUM_AGENTS;
        if (a < 0) a += NUM_AGENTS;
        if (a == agent) {
            int pos = atomicAdd(&tokcount, 1);
            toklist[pos] = i;
        }
    }
    __syncthreads();
    const int cnt = tokcount;
    if (cnt == 0) return;

    const float alpha = fminf(expf(log_alpha[0]), ALPHA_MAX);

    const float* Ua = U + (size_t)agent * HIDDEN * RANK;
    const float* Va = V + (size_t)agent * RANK * HIDDEN;

    const int r2 = t & 15;   // r-pair index (covers r = 2*r2, 2*r2+1)
    const int hs = t >> 4;   // h-slot 0..15
    const int c  = t * 4;    // this thread's 4 output columns

    // gamma/beta for this thread's columns
    const float4 gv = *(const float4*)(gamma + c);
    const float4 bv = *(const float4*)(beta + c);

    for (int it = 0; it < cnt; ++it) {
        const int tok = toklist[it];
        const float* hr = hglob + (size_t)tok * HIDDEN;

        // ---- stage h row into LDS ----
        {
            float4 hv4 = *(const float4*)(hr + c);
            *(float4*)(hrow + c) = hv4;
        }
        __syncthreads();

        // ---- phase 2: inter[r] = sum_hh h[hh] * U[hh][r] ----
        float a0 = 0.f, a1 = 0.f;
        #pragma unroll 4
        for (int hh = hs; hh < HIDDEN; hh += 16) {
            float2 up = *(const float2*)(Ua + hh * RANK + 2 * r2);
            float hv = hrow[hh];
            a0 += hv * up.x;
            a1 += hv * up.y;
        }
        red[hs][2 * r2]     = a0;
        red[hs][2 * r2 + 1] = a1;
        __syncthreads();
        if (t < RANK) {
            float s = 0.f;
            #pragma unroll
            for (int k = 0; k < 16; ++k) s += red[k][t];
            inter[t] = s;
        }
        __syncthreads();

        // ---- phase 3: pert[c..c+3] = sum_r inter[r] * V[r][c..c+3] ----
        float p0 = 0.f, p1 = 0.f, p2 = 0.f, p3 = 0.f;
        #pragma unroll
        for (int r = 0; r < RANK; ++r) {
            float4 vb = *(const float4*)(Va + r * HIDDEN + c);
            float ir = inter[r];
            p0 += ir * vb.x;
            p1 += ir * vb.y;
            p2 += ir * vb.z;
            p3 += ir * vb.w;
        }

        float d0 = hrow[c + 0] + alpha * p0;
        float d1 = hrow[c + 1] + alpha * p1;
        float d2 = hrow[c + 2] + alpha * p2;
        float d3 = hrow[c + 3] + alpha * p3;

        // ---- LayerNorm reduction (sum, sumsq over 1024) ----
        float s = d0 + d1 + d2 + d3;
        float q = d0 * d0 + d1 * d1 + d2 * d2 + d3 * d3;
        #pragma unroll
        for (int off = 32; off > 0; off >>= 1) {
            s += __shfl_xor(s, off, 64);
            q += __shfl_xor(q, off, 64);
        }
        const int wave = t >> 6;
        if ((t & 63) == 0) { wred[wave * 2] = s; wred[wave * 2 + 1] = q; }
        __syncthreads();
        if (t == 0) {
            float S = wred[0] + wred[2] + wred[4] + wred[6];
            float Q = wred[1] + wred[3] + wred[5] + wred[7];
            float mean = S * (1.0f / HIDDEN);
            float var  = Q * (1.0f / HIDDEN) - mean * mean;
            stats[0] = mean;
            stats[1] = rsqrtf(var + LN_EPS);
        }
        __syncthreads();
        const float mean = stats[0];
        const float rstd = stats[1];

        float4 o;
        o.x = (d0 - mean) * rstd * gv.x + bv.x;
        o.y = (d1 - mean) * rstd * gv.y + bv.y;
        o.z = (d2 - mean) * rstd * gv.z + bv.z;
        o.w = (d3 - mean) * rstd * gv.w + bv.w;
        *(float4*)(out + (size_t)tok * HIDDEN + c) = o;
        __syncthreads();   // protect hrow/red/inter before next token
    }
}

extern "C" void kernel_launch(void* const* d_in, const int* in_sizes, int n_in,
                              void* d_out, int out_size, void* d_ws, size_t ws_size,
                              hipStream_t stream) {
    const float* h     = (const float*)d_in[0];
    const float* la    = (const float*)d_in[1];
    const float* gamma = (const float*)d_in[2];
    const float* beta  = (const float*)d_in[3];
    const float* U     = (const float*)d_in[4];
    const float* V     = (const float*)d_in[5];
    const int* ids     = (const int*)d_in[6];
    float* out         = (float*)d_out;

    int ntok = in_sizes[0] / HIDDEN;   // 8192
    div_inject_kernel<<<NUM_AGENTS, 256, 0, stream>>>(h, la, gamma, beta, U, V, ids, out, ntok);
}

// Round 3
// 229.045 us; speedup vs baseline: 1.4419x; 1.4419x over previous
//
#include <hip/hip_runtime.h>
#include <math.h>

#define NUM_AGENTS 256
#define HIDDEN 1024
#define RANK 32
#define NTOK 8192
#define SPLITS 8
#define RANGE (NTOK / SPLITS)   // 1024 tokens per range-split
#define TBATCH 4
#define ALPHA_MAX 5.0f
#define LN_EPS 1e-5f

// Grid: 256 agents x 8 token-range splits = 2048 blocks, 256 threads.
// agent = blockIdx % 256  -> same-agent splits share an XCD (b%8 const per agent)
// Each block: scan its 1024-token id range, collect tokens of its agent,
// process them in groups of 4 with register-batched matvecs:
//   inter[m] = h[m] . U[a];  pert[m] = inter[m] . V[a];
//   out[m] = LayerNorm(h[m] + alpha*pert[m]) * gamma + beta
__global__ __launch_bounds__(256) void div_inject_kernel(
    const float* __restrict__ hglob,
    const float* __restrict__ log_alpha,
    const float* __restrict__ gamma,
    const float* __restrict__ beta,
    const float* __restrict__ U,
    const float* __restrict__ V,
    const int* __restrict__ ids,
    float* __restrict__ out)
{
    __shared__ int toklist[RANGE];
    __shared__ int tokcount;
    __shared__ __align__(16) float Hs[TBATCH][HIDDEN];      // 16 KB
    __shared__ float red[TBATCH][16][RANK];                 // 8 KB
    __shared__ float inter[TBATCH][RANK];
    __shared__ float wred[4][2][TBATCH];                    // [wave][s/q][m]
    __shared__ float stat_mean[TBATCH], stat_rstd[TBATCH];

    const int t = threadIdx.x;
    const int agent = blockIdx.x & (NUM_AGENTS - 1);
    const int split = blockIdx.x >> 8;
    const int base = split * RANGE;

    if (t == 0) tokcount = 0;
    __syncthreads();

    // ---- collect this agent's tokens within our disjoint range ----
    for (int i = t; i < RANGE; i += 256) {
        int idx = base + i;
        int a = ids[idx] & (NUM_AGENTS - 1);   // == mod 256 incl. negatives
        if (a == agent) {
            int pos = atomicAdd(&tokcount, 1);
            toklist[pos] = idx;
        }
    }
    __syncthreads();
    const int cnt = tokcount;
    if (cnt == 0) return;

    const float alpha = fminf(expf(log_alpha[0]), ALPHA_MAX);

    const float* Ua = U + (size_t)agent * HIDDEN * RANK;
    const float* Va = V + (size_t)agent * RANK * HIDDEN;

    const int r2 = t & 15;    // covers r = 2*r2, 2*r2+1
    const int hs = t >> 4;    // h-slice 0..15
    const int c  = t * 4;     // this thread's 4 columns

    const float4 gv = *(const float4*)(gamma + c);
    const float4 bv = *(const float4*)(beta + c);

    for (int g = 0; g < cnt; g += TBATCH) {
        const int nm = min(TBATCH, cnt - g);
        int tk[TBATCH];
        #pragma unroll
        for (int m = 0; m < TBATCH; ++m)
            tk[m] = toklist[g + min(m, nm - 1)];   // pad by replication

        // ---- stage 4 h rows into LDS ----
        #pragma unroll
        for (int m = 0; m < TBATCH; ++m)
            *(float4*)(&Hs[m][c]) = *(const float4*)(hglob + (size_t)tk[m] * HIDDEN + c);
        __syncthreads();

        // ---- phase 2: inter[m][r] = sum_hh Hs[m][hh] * U[hh][r] ----
        float2 acc[TBATCH];
        #pragma unroll
        for (int m = 0; m < TBATCH; ++m) acc[m] = make_float2(0.f, 0.f);
        #pragma unroll 4
        for (int hh = hs; hh < HIDDEN; hh += 16) {
            float2 u = *(const float2*)(Ua + hh * RANK + 2 * r2);
            #pragma unroll
            for (int m = 0; m < TBATCH; ++m) {
                float hv = Hs[m][hh];
                acc[m].x += hv * u.x;
                acc[m].y += hv * u.y;
            }
        }
        #pragma unroll
        for (int m = 0; m < TBATCH; ++m)
            *(float2*)(&red[m][hs][2 * r2]) = acc[m];
        __syncthreads();
        if (t < 128) {
            int m = t >> 5, rr = t & 31;
            float s = 0.f;
            #pragma unroll
            for (int k = 0; k < 16; ++k) s += red[m][k][rr];
            inter[m][rr] = s;
        }
        __syncthreads();

        // ---- phase 3: pert[m][c..c+3] = sum_r inter[m][r] * V[r][c..c+3] ----
        float4 p[TBATCH];
        #pragma unroll
        for (int m = 0; m < TBATCH; ++m) p[m] = make_float4(0.f, 0.f, 0.f, 0.f);
        #pragma unroll 8
        for (int r = 0; r < RANK; ++r) {
            float4 v = *(const float4*)(Va + r * HIDDEN + c);
            #pragma unroll
            for (int m = 0; m < TBATCH; ++m) {
                float ir = inter[m][r];
                p[m].x += ir * v.x;
                p[m].y += ir * v.y;
                p[m].z += ir * v.z;
                p[m].w += ir * v.w;
            }
        }

        // ---- d = h + alpha*pert; batched LayerNorm stats ----
        float4 dmv[TBATCH];
        float s[TBATCH], q[TBATCH];
        #pragma unroll
        for (int m = 0; m < TBATCH; ++m) {
            float4 hv = *(const float4*)(&Hs[m][c]);
            float4 d;
            d.x = hv.x + alpha * p[m].x;
            d.y = hv.y + alpha * p[m].y;
            d.z = hv.z + alpha * p[m].z;
            d.w = hv.w + alpha * p[m].w;
            dmv[m] = d;
            s[m] = d.x + d.y + d.z + d.w;
            q[m] = d.x * d.x + d.y * d.y + d.z * d.z + d.w * d.w;
        }
        #pragma unroll
        for (int off = 32; off > 0; off >>= 1) {
            #pragma unroll
            for (int m = 0; m < TBATCH; ++m) {
                s[m] += __shfl_xor(s[m], off, 64);
                q[m] += __shfl_xor(q[m], off, 64);
            }
        }
        const int wave = t >> 6, lane = t & 63;
        if (lane < TBATCH)               wred[wave][0][lane] = s[lane];
        else if (lane < 2 * TBATCH)      wred[wave][1][lane - TBATCH] = q[lane - TBATCH];
        __syncthreads();
        if (t < TBATCH) {
            float S = wred[0][0][t] + wred[1][0][t] + wred[2][0][t] + wred[3][0][t];
            float Q = wred[0][1][t] + wred[1][1][t] + wred[2][1][t] + wred[3][1][t];
            float mean = S * (1.0f / HIDDEN);
            float var  = Q * (1.0f / HIDDEN) - mean * mean;
            stat_mean[t] = mean;
            stat_rstd[t] = rsqrtf(var + LN_EPS);
        }
        __syncthreads();

        // ---- normalize + write ----
        for (int m = 0; m < nm; ++m) {
            float mean = stat_mean[m], rstd = stat_rstd[m];
            float4 d = dmv[m];
            float4 o;
            o.x = (d.x - mean) * rstd * gv.x + bv.x;
            o.y = (d.y - mean) * rstd * gv.y + bv.y;
            o.z = (d.z - mean) * rstd * gv.z + bv.z;
            o.w = (d.w - mean) * rstd * gv.w + bv.w;
            *(float4*)(out + (size_t)tk[m] * HIDDEN + c) = o;
        }
        __syncthreads();   // protect Hs/red/inter before next group
    }
}

extern "C" void kernel_launch(void* const* d_in, const int* in_sizes, int n_in,
                              void* d_out, int out_size, void* d_ws, size_t ws_size,
                              hipStream_t stream) {
    const float* h     = (const float*)d_in[0];
    const float* la    = (const float*)d_in[1];
    const float* gamma = (const float*)d_in[2];
    const float* beta  = (const float*)d_in[3];
    const float* U     = (const float*)d_in[4];
    const float* V     = (const float*)d_in[5];
    const int* ids     = (const int*)d_in[6];
    float* out         = (float*)d_out;

    div_inject_kernel<<<NUM_AGENTS * SPLITS, 256, 0, stream>>>(
        h, la, gamma, beta, U, V, ids, out);
}

// Round 4
// 222.457 us; speedup vs baseline: 1.4846x; 1.0296x over previous
//
#include <hip/hip_runtime.h>
#include <math.h>

#define NUM_AGENTS 256
#define HIDDEN 1024
#define RANK 32
#define NTOK 8192
#define SPLITS 8
#define RANGE (NTOK / SPLITS)   // 1024 tokens per range-split
#define TBATCH 4
#define ALPHA_MAX 5.0f
#define LN_EPS 1e-5f

// Grid: 256 agents x 8 token-range splits = 2048 blocks, 256 threads.
// Each block: scan its 1024-token id range, collect tokens of its agent,
// process them in groups of 4 with register-batched matvecs:
//   inter[m] = h[m] . U[a];  pert[m] = inter[m] . V[a];
//   out[m] = LayerNorm(h[m] + alpha*pert[m]) * gamma + beta
__global__ __launch_bounds__(256) void div_inject_kernel(
    const float* __restrict__ hglob,
    const float* __restrict__ log_alpha,
    const float* __restrict__ gamma,
    const float* __restrict__ beta,
    const float* __restrict__ U,
    const float* __restrict__ V,
    const int* __restrict__ ids,
    float* __restrict__ out)
{
    __shared__ int toklist[RANGE];                          // 4 KB
    __shared__ int tokcount;
    __shared__ __align__(16) float Hs[TBATCH][HIDDEN];      // 16 KB
    __shared__ __align__(16) float red[4][TBATCH][RANK];    // 2 KB  [wave][m][r]
    __shared__ float inter[TBATCH][RANK];                   // 0.5 KB
    __shared__ float wred[4][2][TBATCH];
    __shared__ float stat_mean[TBATCH], stat_rstd[TBATCH];

    const int t = threadIdx.x;
    const int agent = blockIdx.x & (NUM_AGENTS - 1);
    const int split = blockIdx.x >> 8;
    const int base = split * RANGE;

    if (t == 0) tokcount = 0;
    __syncthreads();

    // ---- collect this agent's tokens within our disjoint range ----
    for (int i = t; i < RANGE; i += 256) {
        int idx = base + i;
        int a = ids[idx] & (NUM_AGENTS - 1);
        if (a == agent) {
            int pos = atomicAdd(&tokcount, 1);
            toklist[pos] = idx;
        }
    }
    __syncthreads();
    const int cnt = tokcount;
    if (cnt == 0) return;

    const float alpha = fminf(expf(log_alpha[0]), ALPHA_MAX);

    const float* Ua = U + (size_t)agent * HIDDEN * RANK;
    const float* Va = V + (size_t)agent * RANK * HIDDEN;

    const int r4 = (t & 7) * 4;   // rank quad: 0,4,...,28
    const int ks = t >> 3;        // k-slice 0..31
    const int c  = t * 4;         // this thread's 4 output columns
    const int wave = t >> 6, lane = t & 63;

    const float4 gv = *(const float4*)(gamma + c);
    const float4 bv = *(const float4*)(beta + c);

    for (int g = 0; g < cnt; g += TBATCH) {
        const int nm = min(TBATCH, cnt - g);
        int tk[TBATCH];
        #pragma unroll
        for (int m = 0; m < TBATCH; ++m)
            tk[m] = toklist[g + min(m, nm - 1)];   // pad by replication

        // ---- stage TBATCH h rows into LDS ----
        #pragma unroll
        for (int m = 0; m < TBATCH; ++m)
            *(float4*)(&Hs[m][c]) = *(const float4*)(hglob + (size_t)tk[m] * HIDDEN + c);
        __syncthreads();

        // ---- phase 2: inter[m][r] = sum_hh Hs[m][hh] * U[hh][r] ----
        // thread covers ranks r4..r4+3 on k-slice hh = ks + 32*j
        float4 acc[TBATCH];
        #pragma unroll
        for (int m = 0; m < TBATCH; ++m) acc[m] = make_float4(0.f, 0.f, 0.f, 0.f);
        #pragma unroll 8
        for (int hh = ks; hh < HIDDEN; hh += 32) {
            float4 u = *(const float4*)(Ua + hh * RANK + r4);
            #pragma unroll
            for (int m = 0; m < TBATCH; ++m) {
                float hv = Hs[m][hh];
                acc[m].x += hv * u.x;
                acc[m].y += hv * u.y;
                acc[m].z += hv * u.z;
                acc[m].w += hv * u.w;
            }
        }
        // reduce over the 8 k-slices within each wave (lanes differing in bits 3..5)
        #pragma unroll
        for (int off = 8; off <= 32; off <<= 1) {
            #pragma unroll
            for (int m = 0; m < TBATCH; ++m) {
                acc[m].x += __shfl_xor(acc[m].x, off, 64);
                acc[m].y += __shfl_xor(acc[m].y, off, 64);
                acc[m].z += __shfl_xor(acc[m].z, off, 64);
                acc[m].w += __shfl_xor(acc[m].w, off, 64);
            }
        }
        if (lane < 8) {
            #pragma unroll
            for (int m = 0; m < TBATCH; ++m)
                *(float4*)(&red[wave][m][r4]) = acc[m];
        }
        __syncthreads();
        if (t < TBATCH * RANK) {
            int m = t >> 5, rr = t & 31;
            inter[m][rr] = red[0][m][rr] + red[1][m][rr] + red[2][m][rr] + red[3][m][rr];
        }
        __syncthreads();

        // ---- phase 3: pert[m][c..c+3] = sum_r inter[m][r] * V[r][c..c+3] ----
        float4 p[TBATCH];
        #pragma unroll
        for (int m = 0; m < TBATCH; ++m) p[m] = make_float4(0.f, 0.f, 0.f, 0.f);
        #pragma unroll 8
        for (int r = 0; r < RANK; ++r) {
            float4 v = *(const float4*)(Va + r * HIDDEN + c);
            #pragma unroll
            for (int m = 0; m < TBATCH; ++m) {
                float ir = inter[m][r];
                p[m].x += ir * v.x;
                p[m].y += ir * v.y;
                p[m].z += ir * v.z;
                p[m].w += ir * v.w;
            }
        }

        // ---- d = h + alpha*pert; batched LayerNorm stats ----
        float4 dmv[TBATCH];
        float s[TBATCH], q[TBATCH];
        #pragma unroll
        for (int m = 0; m < TBATCH; ++m) {
            float4 hv = *(const float4*)(&Hs[m][c]);
            float4 d;
            d.x = hv.x + alpha * p[m].x;
            d.y = hv.y + alpha * p[m].y;
            d.z = hv.z + alpha * p[m].z;
            d.w = hv.w + alpha * p[m].w;
            dmv[m] = d;
            s[m] = d.x + d.y + d.z + d.w;
            q[m] = d.x * d.x + d.y * d.y + d.z * d.z + d.w * d.w;
        }
        #pragma unroll
        for (int off = 32; off > 0; off >>= 1) {
            #pragma unroll
            for (int m = 0; m < TBATCH; ++m) {
                s[m] += __shfl_xor(s[m], off, 64);
                q[m] += __shfl_xor(q[m], off, 64);
            }
        }
        if (lane < TBATCH)               wred[wave][0][lane] = s[lane];
        else if (lane < 2 * TBATCH)      wred[wave][1][lane - TBATCH] = q[lane - TBATCH];
        __syncthreads();
        if (t < TBATCH) {
            float S = wred[0][0][t] + wred[1][0][t] + wred[2][0][t] + wred[3][0][t];
            float Q = wred[0][1][t] + wred[1][1][t] + wred[2][1][t] + wred[3][1][t];
            float mean = S * (1.0f / HIDDEN);
            float var  = Q * (1.0f / HIDDEN) - mean * mean;
            stat_mean[t] = mean;
            stat_rstd[t] = rsqrtf(var + LN_EPS);
        }
        __syncthreads();

        // ---- normalize + write ----
        for (int m = 0; m < nm; ++m) {
            float mean = stat_mean[m], rstd = stat_rstd[m];
            float4 d = dmv[m];
            float4 o;
            o.x = (d.x - mean) * rstd * gv.x + bv.x;
            o.y = (d.y - mean) * rstd * gv.y + bv.y;
            o.z = (d.z - mean) * rstd * gv.z + bv.z;
            o.w = (d.w - mean) * rstd * gv.w + bv.w;
            *(float4*)(out + (size_t)tk[m] * HIDDEN + c) = o;
        }
        __syncthreads();   // protect Hs/red/inter before next group
    }
}

extern "C" void kernel_launch(void* const* d_in, const int* in_sizes, int n_in,
                              void* d_out, int out_size, void* d_ws, size_t ws_size,
                              hipStream_t stream) {
    const float* h     = (const float*)d_in[0];
    const float* la    = (const float*)d_in[1];
    const float* gamma = (const float*)d_in[2];
    const float* beta  = (const float*)d_in[3];
    const float* U     = (const float*)d_in[4];
    const float* V     = (const float*)d_in[5];
    const int* ids     = (const int*)d_in[6];
    float* out         = (float*)d_out;

    div_inject_kernel<<<NUM_AGENTS * SPLITS, 256, 0, stream>>>(
        h, la, gamma, beta, U, V, ids, out);
}